// Round 12
// baseline (418.466 us; speedup 1.0000x reference)
//
#include <hip/hip_runtime.h>
#include <hip/hip_bf16.h>

#define LEAKY 0.2f
#define SCAN_CHUNK 1024
#define BSH 6                      // nodes per bucket = 64

typedef __attribute__((ext_vector_type(2))) _Float16 half2v;
typedef __attribute__((ext_vector_type(8))) _Float16 half8v;

#if __has_builtin(__builtin_amdgcn_fdot2)
__device__ __forceinline__ float fdot2(half2v a, half2v b, float c) {
    return __builtin_amdgcn_fdot2(a, b, c, false);
}
#else
__device__ __forceinline__ float fdot2(half2v a, half2v b, float c) {
    return c + (float)a[0] * (float)b[0] + (float)a[1] * (float)b[1];
}
#endif

// ---------- bf16 bit helpers ----------
__device__ __forceinline__ unsigned short bf16bits(float f) {
    __hip_bfloat16 h = __float2bfloat16(f);
    return *reinterpret_cast<unsigned short*>(&h);
}
__device__ __forceinline__ float bf16val(unsigned short u) {
    unsigned v = (unsigned)u << 16;
    return __uint_as_float(v);
}

// ==================== CSR build: bucketed counting sort ====================
__global__ void zeroi(int* __restrict__ p, int n) {
    int i = blockIdx.x * blockDim.x + threadIdx.x;
    if (i < n) p[i] = 0;
}

// Phase 1: append (src,dst) into per-bucket segment. 782 hot cursors in L2;
// writes dense per bucket (active-line set ~50KB) — avoids 16x line amplification.
__global__ void bucket_scatter(const int* __restrict__ src, const int* __restrict__ dst,
                               int* __restrict__ bcur, uint2* __restrict__ ebuf,
                               int E, int CAP) {
    int e = blockIdx.x * blockDim.x + threadIdx.x;
    if (e >= E) return;
    int d = dst[e];
    int b = d >> BSH;
    int p = atomicAdd(&bcur[b], 1);
    if (p >= CAP) p = CAP - 1;    // statistically unreachable (mean+16 sigma cap)
    ebuf[(size_t)b * CAP + p] = make_uint2((unsigned)src[e], (unsigned)d);
}

// Phase 2: per-bucket LDS histogram -> dense cnt write (replaces global atomic hist).
__global__ __launch_bounds__(256) void bucket_count(const uint2* __restrict__ ebuf,
                                                    const int* __restrict__ bcur,
                                                    int* __restrict__ cnt, int N, int CAP) {
    __shared__ int h[64];
    const int b  = blockIdx.x;
    const int n0 = b << BSH;
    const int t  = threadIdx.x;
    if (t < 64) h[t] = 0;
    __syncthreads();
    const int ne = min(bcur[b], CAP);
    const uint2* __restrict__ eb = ebuf + (size_t)b * CAP;
    for (int i = t; i < ne; i += 256) {
        atomicAdd(&h[(int)eb[i].y & 63], 1);
    }
    __syncthreads();
    if (t < 64 && n0 + t < N) cnt[n0 + t] = h[t];
}

// Phase 3: per-bucket LDS rank -> csrc write confined to the bucket's
// contiguous region (~4KB, single L2, lines fill).
__global__ __launch_bounds__(256) void bucket_place(const uint2* __restrict__ ebuf,
                                                    const int* __restrict__ bcur,
                                                    const int* __restrict__ rowptr,
                                                    int* __restrict__ csrc, int N, int CAP) {
    __shared__ int r[64];
    __shared__ int base[64];
    const int b  = blockIdx.x;
    const int n0 = b << BSH;
    const int t  = threadIdx.x;
    if (t < 64) {
        r[t] = 0;
        base[t] = (n0 + t < N) ? rowptr[n0 + t] : 0;
    }
    __syncthreads();
    const int ne = min(bcur[b], CAP);
    const uint2* __restrict__ eb = ebuf + (size_t)b * CAP;
    for (int i = t; i < ne; i += 256) {
        uint2 ed_ = eb[i];
        int li = (int)ed_.y & 63;
        int rk = atomicAdd(&r[li], 1);
        csrc[base[li] + rk] = (int)ed_.x;
    }
}

// ---------- scans (cnt -> rowptr) ----------
__global__ __launch_bounds__(256) void scan1(const int* __restrict__ cnt, int* __restrict__ part,
                                             int* __restrict__ bsum, int n) {
    __shared__ int s[256];
    const int base = blockIdx.x * SCAN_CHUNK;
    const int t = threadIdx.x;
    int v[4], sum = 0;
    #pragma unroll
    for (int i = 0; i < 4; ++i) {
        int idx = base + t * 4 + i;
        v[i] = (idx < n) ? cnt[idx] : 0;
        sum += v[i];
    }
    s[t] = sum;
    __syncthreads();
    for (int off = 1; off < 256; off <<= 1) {
        int x = (t >= off) ? s[t - off] : 0;
        __syncthreads();
        s[t] += x;
        __syncthreads();
    }
    int excl = (t == 0) ? 0 : s[t - 1];
    if (t == 255) bsum[blockIdx.x] = s[255];
    #pragma unroll
    for (int i = 0; i < 4; ++i) {
        int idx = base + t * 4 + i;
        if (idx < n) part[idx] = excl;
        excl += v[i];
    }
}

__global__ __launch_bounds__(256) void scan2(int* __restrict__ bsum, int nb) {
    __shared__ int s[256];
    const int t = threadIdx.x;
    s[t] = (t < nb) ? bsum[t] : 0;
    __syncthreads();
    for (int off = 1; off < 256; off <<= 1) {
        int x = (t >= off) ? s[t - off] : 0;
        __syncthreads();
        s[t] += x;
        __syncthreads();
    }
    if (t < nb) bsum[t] = (t == 0) ? 0 : s[t - 1];
}

__global__ void scan3(const int* __restrict__ part, const int* __restrict__ bsum,
                      int* __restrict__ rowptr, int n, int E) {
    int i = blockIdx.x * blockDim.x + threadIdx.x;
    if (i < n) rowptr[i] = part[i] + bsum[i / SCAN_CHUNK];
    if (i == n) rowptr[n] = E;
}

// ==================== z = X @ W — f16 operands, v_dot2 fp32 accum ====================
template<int COLS>
__global__ __launch_bounds__(16 * COLS / 4) void gemm_t(
    const float* __restrict__ X, const float* __restrict__ W,
    float* __restrict__ Z, unsigned short* __restrict__ Zb, int N, int HD)
{
    constexpr int TC = COLS / 4;
    constexpr int NT = 16 * TC;
    __shared__ __align__(16) half2v XsT[64][68];
    __shared__ __align__(16) half2v Ws2[64][COLS];

    const int tid  = threadIdx.x;
    const int row0 = blockIdx.x * 64;
    const int col0 = blockIdx.y * COLS;

    for (int i = tid; i < 64 * 32; i += NT) {
        const int row = i >> 5, kq = i & 31;
        float4 xv = make_float4(0.f, 0.f, 0.f, 0.f);
        if (row0 + row < N) xv = *(const float4*)&X[(size_t)(row0 + row) * 128 + kq * 4];
        half2v a; a[0] = (_Float16)xv.x; a[1] = (_Float16)xv.y;
        half2v b; b[0] = (_Float16)xv.z; b[1] = (_Float16)xv.w;
        XsT[kq * 2][row]     = a;
        XsT[kq * 2 + 1][row] = b;
    }
    for (int i = tid; i < 64 * COLS; i += NT) {
        const int kp = i / COLS, c = i % COLS;
        const int hd = col0 + c;
        const size_t base = (size_t)(hd >> 5) * (128 * 32) + (hd & 31);
        half2v wv;
        wv[0] = (_Float16)W[base + (size_t)(2 * kp) * 32];
        wv[1] = (_Float16)W[base + (size_t)(2 * kp + 1) * 32];
        Ws2[kp][c] = wv;
    }
    __syncthreads();

    const int tr = tid / TC;
    const int tc = tid % TC;

    float acc[4][4] = {};
    #pragma unroll 4
    for (int kp = 0; kp < 64; ++kp) {
        half8v xv = *(const half8v*)&XsT[kp][tr * 4];
        half8v wv = *(const half8v*)&Ws2[kp][tc * 4];
        #pragma unroll
        for (int i = 0; i < 4; ++i) {
            half2v xi; xi[0] = xv[2 * i]; xi[1] = xv[2 * i + 1];
            #pragma unroll
            for (int j = 0; j < 4; ++j) {
                half2v wj; wj[0] = wv[2 * j]; wj[1] = wv[2 * j + 1];
                acc[i][j] = fdot2(xi, wj, acc[i][j]);
            }
        }
    }

    #pragma unroll
    for (int i = 0; i < 4; ++i) {
        const int row = row0 + tr * 4 + i;
        if (row < N) {
            float4 o = make_float4(acc[i][0], acc[i][1], acc[i][2], acc[i][3]);
            *(float4*)&Z[(size_t)row * HD + col0 + tc * 4] = o;
            ushort4 ub;
            ub.x = bf16bits(o.x); ub.y = bf16bits(o.y);
            ub.z = bf16bits(o.z); ub.w = bf16bits(o.w);
            *(ushort4*)&Zb[(size_t)row * HD + col0 + tc * 4] = ub;
        }
    }
}

// ==================== es/ed = z · a (fp32 z) ====================
__global__ void attn_coef(const float* __restrict__ Z, const float* __restrict__ a,
                          float* __restrict__ es, float* __restrict__ ed,
                          int NH, int H) {
    int i = blockIdx.x * blockDim.x + threadIdx.x;
    if (i >= NH) return;
    int h = i % H;
    const float* zp = Z + (size_t)i * 32;
    const float* as = a + (size_t)h * 64;
    const float* ad = as + 32;
    float s = 0.0f, d_ = 0.0f;
    #pragma unroll
    for (int d = 0; d < 32; d += 4) {
        float4 zv = *(const float4*)&zp[d];
        float4 av = *(const float4*)&as[d];
        float4 dv = *(const float4*)&ad[d];
        s  += zv.x * av.x + zv.y * av.y + zv.z * av.z + zv.w * av.w;
        d_ += zv.x * dv.x + zv.y * dv.y + zv.z * dv.z + zv.w * dv.w;
    }
    es[i] = s;
    ed[i] = d_;
}

// ==================== fused per-node GAT, wide ushort4 gathers ====================
__global__ __launch_bounds__(256) void gat_node4(
    const unsigned short* __restrict__ Zb, const float* __restrict__ es,
    const float* __restrict__ ed, const int* __restrict__ rowptr,
    const int* __restrict__ csrc, float* __restrict__ Hout, int N)
{
    const int lane = threadIdx.x & 63;
    const int node = (blockIdx.x * blockDim.x + threadIdx.x) >> 6;
    if (node >= N) return;

    const int half = lane >> 5;
    const int cl   = lane & 31;
    const int head = cl >> 3;
    const float edv = ed[node * 4 + head];
    const int beg = rowptr[node];
    const int deg = rowptr[node + 1] - beg;
    const int* __restrict__ cp = csrc + beg;

    float4 acc = make_float4(0.f, 0.f, 0.f, 0.f);
    float den = 0.f;

    int j = 0;
    for (; j + 4 <= deg; j += 4) {
        const int sA = cp[j + half];
        const int sB = cp[j + 2 + half];
        const float qA = es[(unsigned)sA * 4u + head];
        const float qB = es[(unsigned)sB * 4u + head];
        const ushort4 uA = *(const ushort4*)&Zb[(unsigned)sA * 128u + cl * 4];
        const ushort4 uB = *(const ushort4*)&Zb[(unsigned)sB * 128u + cl * 4];
        float eA = qA + edv; eA = fmaxf(eA, LEAKY * eA);
        float eB = qB + edv; eB = fmaxf(eB, LEAKY * eB);
        const float pA = __expf(eA), pB = __expf(eB);
        den += pA + pB;
        acc.x = fmaf(pA, bf16val(uA.x), acc.x);
        acc.y = fmaf(pA, bf16val(uA.y), acc.y);
        acc.z = fmaf(pA, bf16val(uA.z), acc.z);
        acc.w = fmaf(pA, bf16val(uA.w), acc.w);
        acc.x = fmaf(pB, bf16val(uB.x), acc.x);
        acc.y = fmaf(pB, bf16val(uB.y), acc.y);
        acc.z = fmaf(pB, bf16val(uB.z), acc.z);
        acc.w = fmaf(pB, bf16val(uB.w), acc.w);
    }
    {
        const int ja = j + half;
        if (ja < deg) {
            const int s = cp[ja];
            const float q = es[(unsigned)s * 4u + head];
            const ushort4 u = *(const ushort4*)&Zb[(unsigned)s * 128u + cl * 4];
            float e = q + edv; e = fmaxf(e, LEAKY * e);
            const float p = __expf(e);
            den += p;
            acc.x = fmaf(p, bf16val(u.x), acc.x);
            acc.y = fmaf(p, bf16val(u.y), acc.y);
            acc.z = fmaf(p, bf16val(u.z), acc.z);
            acc.w = fmaf(p, bf16val(u.w), acc.w);
        }
        const int jb = j + 2 + half;
        if (jb < deg) {
            const int s = cp[jb];
            const float q = es[(unsigned)s * 4u + head];
            const ushort4 u = *(const ushort4*)&Zb[(unsigned)s * 128u + cl * 4];
            float e = q + edv; e = fmaxf(e, LEAKY * e);
            const float p = __expf(e);
            den += p;
            acc.x = fmaf(p, bf16val(u.x), acc.x);
            acc.y = fmaf(p, bf16val(u.y), acc.y);
            acc.z = fmaf(p, bf16val(u.z), acc.z);
            acc.w = fmaf(p, bf16val(u.w), acc.w);
        }
    }

    den   += __shfl_xor(den, 32);
    acc.x += __shfl_xor(acc.x, 32);
    acc.y += __shfl_xor(acc.y, 32);
    acc.z += __shfl_xor(acc.z, 32);
    acc.w += __shfl_xor(acc.w, 32);

    if (half == 0) {
        float4 o;
        if (deg > 0) {
            const float r = 1.0f / den;
            o = make_float4(acc.x * r, acc.y * r, acc.z * r, acc.w * r);
        } else {
            o = make_float4(0.f, 0.f, 0.f, 0.f);
        }
        *(float4*)&Hout[(size_t)node * 128 + cl * 4] = o;
    }
}

__global__ __launch_bounds__(256) void gat_node1(
    const unsigned short* __restrict__ Zb, const float* __restrict__ es,
    const float* __restrict__ ed, const int* __restrict__ rowptr,
    const int* __restrict__ csrc, float* __restrict__ Hout, int N)
{
    const int lane = threadIdx.x & 63;
    const int node = (blockIdx.x * blockDim.x + threadIdx.x) >> 6;
    if (node >= N) return;

    const int grp = lane >> 3;
    const int cl  = lane & 7;
    const float edv = ed[node];
    const int beg = rowptr[node];
    const int deg = rowptr[node + 1] - beg;
    const int* __restrict__ cp = csrc + beg;

    float4 acc = make_float4(0.f, 0.f, 0.f, 0.f);
    float den = 0.f;

    int j = 0;
    for (; j + 8 <= deg; j += 8) {
        const int s = cp[j + grp];
        const float q = es[s];
        const ushort4 u = *(const ushort4*)&Zb[(unsigned)s * 32u + cl * 4];
        float e = q + edv; e = fmaxf(e, LEAKY * e);
        const float p = __expf(e);
        den += p;
        acc.x = fmaf(p, bf16val(u.x), acc.x);
        acc.y = fmaf(p, bf16val(u.y), acc.y);
        acc.z = fmaf(p, bf16val(u.z), acc.z);
        acc.w = fmaf(p, bf16val(u.w), acc.w);
    }
    {
        const int jt = j + grp;
        if (jt < deg) {
            const int s = cp[jt];
            const float q = es[s];
            const ushort4 u = *(const ushort4*)&Zb[(unsigned)s * 32u + cl * 4];
            float e = q + edv; e = fmaxf(e, LEAKY * e);
            const float p = __expf(e);
            den += p;
            acc.x = fmaf(p, bf16val(u.x), acc.x);
            acc.y = fmaf(p, bf16val(u.y), acc.y);
            acc.z = fmaf(p, bf16val(u.z), acc.z);
            acc.w = fmaf(p, bf16val(u.w), acc.w);
        }
    }

    #pragma unroll
    for (int off = 8; off < 64; off <<= 1) {
        den   += __shfl_xor(den, off);
        acc.x += __shfl_xor(acc.x, off);
        acc.y += __shfl_xor(acc.y, off);
        acc.z += __shfl_xor(acc.z, off);
        acc.w += __shfl_xor(acc.w, off);
    }

    if (grp == 0) {
        float4 o;
        if (deg > 0) {
            const float r = 1.0f / den;
            o = make_float4(acc.x * r, acc.y * r, acc.z * r, acc.w * r);
        } else {
            o = make_float4(0.f, 0.f, 0.f, 0.f);
        }
        *(float4*)&Hout[(size_t)node * 32 + cl * 4] = o;
    }
}

// =========================== launch ===========================
extern "C" void kernel_launch(void* const* d_in, const int* in_sizes, int n_in,
                              void* d_out, int out_size, void* d_ws, size_t ws_size,
                              hipStream_t stream) {
    const float* features = (const float*)d_in[0];
    const float* W1 = (const float*)d_in[1];
    const float* a1 = (const float*)d_in[2];
    const float* W2 = (const float*)d_in[3];
    const float* a2 = (const float*)d_in[4];
    const int*   src = (const int*)d_in[5];
    const int*   dst = (const int*)d_in[6];
    float* out = (float*)d_out;

    const int N  = in_sizes[0] / 128;   // 50000
    const int E  = in_sizes[5];         // 800000
    const int H1 = in_sizes[2] / 64;    // 4

    const int NB  = (N + 63) >> BSH;                      // 782 buckets
    const int CAP = (((E / NB) * 3 / 2) + 255) & ~255;    // ~1.5x mean, 256-mult (1536)

    // ---- workspace layout (16B-aligned blocks) ----
    char* wsb = (char*)d_ws;
    size_t ob = 0;
    auto alloc_b = [&](size_t bytes) {
        ob = (ob + 15) & ~(size_t)15;
        char* p = wsb + ob; ob += bytes; return p;
    };

    int* cnt    = (int*)alloc_b((size_t)(N + NB) * 4);    // cnt[N] + bcur[NB], zeroed together
    int* bcur   = cnt + N;
    int* part   = (int*)alloc_b((size_t)N * 4);
    int* bsum   = (int*)alloc_b(256 * 4);
    int* rowptr = (int*)alloc_b((size_t)(N + 1) * 4);
    int* csrc   = (int*)alloc_b((size_t)E * 4);
    float* z1   = (float*)alloc_b((size_t)N * 128 * 4);
    float* h1   = (float*)alloc_b((size_t)N * 128 * 4);
    float* es1  = (float*)alloc_b((size_t)N * H1 * 4);
    float* ed1  = (float*)alloc_b((size_t)N * H1 * 4);
    float* z2   = (float*)alloc_b((size_t)N * 32 * 4);
    float* es2  = (float*)alloc_b((size_t)N * 4);
    float* ed2  = (float*)alloc_b((size_t)N * 4);
    unsigned short* zb1 = (unsigned short*)alloc_b((size_t)N * 128 * 2);
    unsigned short* zb2 = (unsigned short*)alloc_b((size_t)N * 32 * 2);

    // ebuf aliases z1: CSR build completes before gemm_t writes z1 (stream-ordered).
    // size: NB*CAP*8 = 782*1536*8 = 9.6MB <= N*128*4 = 25.6MB.
    uint2* ebuf = (uint2*)z1;

    const int B = 256;
    #define GRID(n) (((n) + B - 1) / B)
    const int nb = (N + SCAN_CHUNK - 1) / SCAN_CHUNK;

    // ---- CSR build (bucketed counting sort; reused by both layers) ----
    zeroi<<<GRID(N + NB), B, 0, stream>>>(cnt, N + NB);
    bucket_scatter<<<GRID(E), B, 0, stream>>>(src, dst, bcur, ebuf, E, CAP);
    bucket_count<<<NB, 256, 0, stream>>>(ebuf, bcur, cnt, N, CAP);
    scan1<<<nb, B, 0, stream>>>(cnt, part, bsum, N);
    scan2<<<1, B, 0, stream>>>(bsum, nb);
    scan3<<<GRID(N + 1), B, 0, stream>>>(part, bsum, rowptr, N, E);
    bucket_place<<<NB, 256, 0, stream>>>(ebuf, bcur, rowptr, csrc, N, CAP);

    const int RB = (N + 63) / 64;   // 782 row blocks

    // ---- layer 1 (H=4, HD=128) ----
    gemm_t<64><<<dim3(RB, 2), 256, 0, stream>>>(features, W1, z1, zb1, N, 128);
    attn_coef<<<GRID(N * H1), B, 0, stream>>>(z1, a1, es1, ed1, N * H1, H1);
    gat_node4<<<GRID(N * 64), B, 0, stream>>>(zb1, es1, ed1, rowptr, csrc, h1, N);

    // ---- layer 2 (H=1, HD=32) ----
    gemm_t<32><<<dim3(RB, 1), 128, 0, stream>>>(h1, W2, z2, zb2, N, 32);
    attn_coef<<<GRID(N), B, 0, stream>>>(z2, a2, es2, ed2, N, 1);
    gat_node1<<<GRID(N * 64), B, 0, stream>>>(zb2, es2, ed2, rowptr, csrc, out, N);

    #undef GRID
    (void)n_in; (void)out_size; (void)ws_size;
}

// Round 15
// 248.792 us; speedup vs baseline: 1.6820x; 1.6820x over previous
//
#include <hip/hip_runtime.h>
#include <hip/hip_bf16.h>

#define LEAKY 0.2f
#define SCAN_CHUNK 1024
#define BSH 6                      // nodes per bucket = 64
#define NBMAX 1024                 // max buckets (LDS arrays)
#define SORTB 256                  // blocks in the stable counting sort

typedef __attribute__((ext_vector_type(2))) _Float16 half2v;
typedef __attribute__((ext_vector_type(8))) _Float16 half8v;

#if __has_builtin(__builtin_amdgcn_fdot2)
__device__ __forceinline__ float fdot2(half2v a, half2v b, float c) {
    return __builtin_amdgcn_fdot2(a, b, c, false);
}
#else
__device__ __forceinline__ float fdot2(half2v a, half2v b, float c) {
    return c + (float)a[0] * (float)b[0] + (float)a[1] * (float)b[1];
}
#endif

// ---------- bf16 bit helpers ----------
__device__ __forceinline__ unsigned short bf16bits(float f) {
    __hip_bfloat16 h = __float2bfloat16(f);
    return *reinterpret_cast<unsigned short*>(&h);
}
__device__ __forceinline__ float bf16val(unsigned short u) {
    unsigned v = (unsigned)u << 16;
    return __uint_as_float(v);
}

// ==================== CSR build: atomic-free stable bucket sort ====================
// r12 post-mortem: 800K global atomics over 782 cursors = 1023-deep same-address
// serialization (~190ns each) = 190us. Fix: per-block LDS histograms + scan —
// ZERO global atomics.

// Pass 1: per-block LDS histogram over buckets; dense write hist[blk][b].
__global__ __launch_bounds__(256) void hist_blk(const int* __restrict__ dst,
                                                int* __restrict__ hist,
                                                int E, int NB, int CPB) {
    __shared__ int h[NBMAX];
    const int blk = blockIdx.x, t = threadIdx.x;
    for (int i = t; i < NB; i += 256) h[i] = 0;
    __syncthreads();
    const int e0 = blk * CPB, e1 = min(e0 + CPB, E);
    for (int e = e0 + t; e < e1; e += 256) atomicAdd(&h[dst[e] >> BSH], 1);
    __syncthreads();
    int* __restrict__ hr = hist + (size_t)blk * NB;
    for (int i = t; i < NB; i += 256) hr[i] = h[i];
}

// Pass 2: one wave per bucket — exclusive prefix of hist[·][b] over blocks
// (in place), total -> bcur[b]. shfl-scan in chunks of 64.
__global__ __launch_bounds__(256) void col_scan(int* __restrict__ hist,
                                                int* __restrict__ bcur,
                                                int NB, int B) {
    const int lane = threadIdx.x & 63;
    const int b = (blockIdx.x * blockDim.x + threadIdx.x) >> 6;
    if (b >= NB) return;
    int run = 0;
    for (int base = 0; base < B; base += 64) {
        const int blk = base + lane;
        const int v = (blk < B) ? hist[(size_t)blk * NB + b] : 0;
        int s = v;
        #pragma unroll
        for (int off = 1; off < 64; off <<= 1) {
            int x = __shfl_up(s, off);
            if (lane >= off) s += x;
        }
        if (blk < B) hist[(size_t)blk * NB + b] = run + s - v;   // exclusive
        run += __shfl(s, 63);
    }
    if (lane == 0) bcur[b] = run;
}

// Pass 3: re-read edges; LDS cursors seeded from hist[blk][·]; place into
// ebuf bucket regions (CAP-strided). LDS atomics only (~4-deep).
__global__ __launch_bounds__(256) void place_blk(const int* __restrict__ src,
                                                 const int* __restrict__ dst,
                                                 const int* __restrict__ hist,
                                                 uint2* __restrict__ ebuf,
                                                 int E, int NB, int CPB, int CAP) {
    __shared__ int cur[NBMAX];
    const int blk = blockIdx.x, t = threadIdx.x;
    const int* __restrict__ hr = hist + (size_t)blk * NB;
    for (int i = t; i < NB; i += 256) cur[i] = hr[i];
    __syncthreads();
    const int e0 = blk * CPB, e1 = min(e0 + CPB, E);
    for (int e = e0 + t; e < e1; e += 256) {
        const int d = dst[e];
        const int b = d >> BSH;
        int pos = atomicAdd(&cur[b], 1);
        if (pos >= CAP) pos = CAP - 1;   // statistically unreachable
        ebuf[(size_t)b * CAP + pos] = make_uint2((unsigned)src[e], (unsigned)d);
    }
}

// Per-bucket LDS histogram -> dense cnt write.
__global__ __launch_bounds__(256) void bucket_count(const uint2* __restrict__ ebuf,
                                                    const int* __restrict__ bcur,
                                                    int* __restrict__ cnt, int N, int CAP) {
    __shared__ int h[64];
    const int b  = blockIdx.x;
    const int n0 = b << BSH;
    const int t  = threadIdx.x;
    if (t < 64) h[t] = 0;
    __syncthreads();
    const int ne = min(bcur[b], CAP);
    const uint2* __restrict__ eb = ebuf + (size_t)b * CAP;
    for (int i = t; i < ne; i += 256) {
        atomicAdd(&h[(int)eb[i].y & 63], 1);
    }
    __syncthreads();
    if (t < 64 && n0 + t < N) cnt[n0 + t] = h[t];
}

// Per-bucket LDS rank -> csrc write confined to bucket's contiguous region.
__global__ __launch_bounds__(256) void bucket_place(const uint2* __restrict__ ebuf,
                                                    const int* __restrict__ bcur,
                                                    const int* __restrict__ rowptr,
                                                    int* __restrict__ csrc, int N, int CAP) {
    __shared__ int r[64];
    __shared__ int base[64];
    const int b  = blockIdx.x;
    const int n0 = b << BSH;
    const int t  = threadIdx.x;
    if (t < 64) {
        r[t] = 0;
        base[t] = (n0 + t < N) ? rowptr[n0 + t] : 0;
    }
    __syncthreads();
    const int ne = min(bcur[b], CAP);
    const uint2* __restrict__ eb = ebuf + (size_t)b * CAP;
    for (int i = t; i < ne; i += 256) {
        uint2 ed_ = eb[i];
        int li = (int)ed_.y & 63;
        int rk = atomicAdd(&r[li], 1);
        csrc[base[li] + rk] = (int)ed_.x;
    }
}

// ---------- scans (cnt -> rowptr) ----------
__global__ __launch_bounds__(256) void scan1(const int* __restrict__ cnt, int* __restrict__ part,
                                             int* __restrict__ bsum, int n) {
    __shared__ int s[256];
    const int base = blockIdx.x * SCAN_CHUNK;
    const int t = threadIdx.x;
    int v[4], sum = 0;
    #pragma unroll
    for (int i = 0; i < 4; ++i) {
        int idx = base + t * 4 + i;
        v[i] = (idx < n) ? cnt[idx] : 0;
        sum += v[i];
    }
    s[t] = sum;
    __syncthreads();
    for (int off = 1; off < 256; off <<= 1) {
        int x = (t >= off) ? s[t - off] : 0;
        __syncthreads();
        s[t] += x;
        __syncthreads();
    }
    int excl = (t == 0) ? 0 : s[t - 1];
    if (t == 255) bsum[blockIdx.x] = s[255];
    #pragma unroll
    for (int i = 0; i < 4; ++i) {
        int idx = base + t * 4 + i;
        if (idx < n) part[idx] = excl;
        excl += v[i];
    }
}

__global__ __launch_bounds__(256) void scan2(int* __restrict__ bsum, int nb) {
    __shared__ int s[256];
    const int t = threadIdx.x;
    s[t] = (t < nb) ? bsum[t] : 0;
    __syncthreads();
    for (int off = 1; off < 256; off <<= 1) {
        int x = (t >= off) ? s[t - off] : 0;
        __syncthreads();
        s[t] += x;
        __syncthreads();
    }
    if (t < nb) bsum[t] = (t == 0) ? 0 : s[t - 1];
}

__global__ void scan3(const int* __restrict__ part, const int* __restrict__ bsum,
                      int* __restrict__ rowptr, int n, int E) {
    int i = blockIdx.x * blockDim.x + threadIdx.x;
    if (i < n) rowptr[i] = part[i] + bsum[i / SCAN_CHUNK];
    if (i == n) rowptr[n] = E;
}

// ==================== z = X @ W — f16 operands, v_dot2 fp32 accum ====================
template<int COLS>
__global__ __launch_bounds__(16 * COLS / 4) void gemm_t(
    const float* __restrict__ X, const float* __restrict__ W,
    float* __restrict__ Z, unsigned short* __restrict__ Zb, int N, int HD)
{
    constexpr int TC = COLS / 4;
    constexpr int NT = 16 * TC;
    __shared__ __align__(16) half2v XsT[64][68];
    __shared__ __align__(16) half2v Ws2[64][COLS];

    const int tid  = threadIdx.x;
    const int row0 = blockIdx.x * 64;
    const int col0 = blockIdx.y * COLS;

    for (int i = tid; i < 64 * 32; i += NT) {
        const int row = i >> 5, kq = i & 31;
        float4 xv = make_float4(0.f, 0.f, 0.f, 0.f);
        if (row0 + row < N) xv = *(const float4*)&X[(size_t)(row0 + row) * 128 + kq * 4];
        half2v a; a[0] = (_Float16)xv.x; a[1] = (_Float16)xv.y;
        half2v b; b[0] = (_Float16)xv.z; b[1] = (_Float16)xv.w;
        XsT[kq * 2][row]     = a;
        XsT[kq * 2 + 1][row] = b;
    }
    for (int i = tid; i < 64 * COLS; i += NT) {
        const int kp = i / COLS, c = i % COLS;
        const int hd = col0 + c;
        const size_t base = (size_t)(hd >> 5) * (128 * 32) + (hd & 31);
        half2v wv;
        wv[0] = (_Float16)W[base + (size_t)(2 * kp) * 32];
        wv[1] = (_Float16)W[base + (size_t)(2 * kp + 1) * 32];
        Ws2[kp][c] = wv;
    }
    __syncthreads();

    const int tr = tid / TC;
    const int tc = tid % TC;

    float acc[4][4] = {};
    #pragma unroll 4
    for (int kp = 0; kp < 64; ++kp) {
        half8v xv = *(const half8v*)&XsT[kp][tr * 4];
        half8v wv = *(const half8v*)&Ws2[kp][tc * 4];
        #pragma unroll
        for (int i = 0; i < 4; ++i) {
            half2v xi; xi[0] = xv[2 * i]; xi[1] = xv[2 * i + 1];
            #pragma unroll
            for (int j = 0; j < 4; ++j) {
                half2v wj; wj[0] = wv[2 * j]; wj[1] = wv[2 * j + 1];
                acc[i][j] = fdot2(xi, wj, acc[i][j]);
            }
        }
    }

    #pragma unroll
    for (int i = 0; i < 4; ++i) {
        const int row = row0 + tr * 4 + i;
        if (row < N) {
            float4 o = make_float4(acc[i][0], acc[i][1], acc[i][2], acc[i][3]);
            *(float4*)&Z[(size_t)row * HD + col0 + tc * 4] = o;
            ushort4 ub;
            ub.x = bf16bits(o.x); ub.y = bf16bits(o.y);
            ub.z = bf16bits(o.z); ub.w = bf16bits(o.w);
            *(ushort4*)&Zb[(size_t)row * HD + col0 + tc * 4] = ub;
        }
    }
}

// ==================== es/ed = z · a (fp32 z) ====================
__global__ void attn_coef(const float* __restrict__ Z, const float* __restrict__ a,
                          float* __restrict__ es, float* __restrict__ ed,
                          int NH, int H) {
    int i = blockIdx.x * blockDim.x + threadIdx.x;
    if (i >= NH) return;
    int h = i % H;
    const float* zp = Z + (size_t)i * 32;
    const float* as = a + (size_t)h * 64;
    const float* ad = as + 32;
    float s = 0.0f, d_ = 0.0f;
    #pragma unroll
    for (int d = 0; d < 32; d += 4) {
        float4 zv = *(const float4*)&zp[d];
        float4 av = *(const float4*)&as[d];
        float4 dv = *(const float4*)&ad[d];
        s  += zv.x * av.x + zv.y * av.y + zv.z * av.z + zv.w * av.w;
        d_ += zv.x * dv.x + zv.y * dv.y + zv.z * dv.z + zv.w * dv.w;
    }
    es[i] = s;
    ed[i] = d_;
}

// ==================== fused per-node GAT, wide ushort4 gathers ====================
__global__ __launch_bounds__(256) void gat_node4(
    const unsigned short* __restrict__ Zb, const float* __restrict__ es,
    const float* __restrict__ ed, const int* __restrict__ rowptr,
    const int* __restrict__ csrc, float* __restrict__ Hout, int N)
{
    const int lane = threadIdx.x & 63;
    const int node = (blockIdx.x * blockDim.x + threadIdx.x) >> 6;
    if (node >= N) return;

    const int half = lane >> 5;
    const int cl   = lane & 31;
    const int head = cl >> 3;
    const float edv = ed[node * 4 + head];
    const int beg = rowptr[node];
    const int deg = rowptr[node + 1] - beg;
    const int* __restrict__ cp = csrc + beg;

    float4 acc = make_float4(0.f, 0.f, 0.f, 0.f);
    float den = 0.f;

    int j = 0;
    for (; j + 4 <= deg; j += 4) {
        const int sA = cp[j + half];
        const int sB = cp[j + 2 + half];
        const float qA = es[(unsigned)sA * 4u + head];
        const float qB = es[(unsigned)sB * 4u + head];
        const ushort4 uA = *(const ushort4*)&Zb[(unsigned)sA * 128u + cl * 4];
        const ushort4 uB = *(const ushort4*)&Zb[(unsigned)sB * 128u + cl * 4];
        float eA = qA + edv; eA = fmaxf(eA, LEAKY * eA);
        float eB = qB + edv; eB = fmaxf(eB, LEAKY * eB);
        const float pA = __expf(eA), pB = __expf(eB);
        den += pA + pB;
        acc.x = fmaf(pA, bf16val(uA.x), acc.x);
        acc.y = fmaf(pA, bf16val(uA.y), acc.y);
        acc.z = fmaf(pA, bf16val(uA.z), acc.z);
        acc.w = fmaf(pA, bf16val(uA.w), acc.w);
        acc.x = fmaf(pB, bf16val(uB.x), acc.x);
        acc.y = fmaf(pB, bf16val(uB.y), acc.y);
        acc.z = fmaf(pB, bf16val(uB.z), acc.z);
        acc.w = fmaf(pB, bf16val(uB.w), acc.w);
    }
    {
        const int ja = j + half;
        if (ja < deg) {
            const int s = cp[ja];
            const float q = es[(unsigned)s * 4u + head];
            const ushort4 u = *(const ushort4*)&Zb[(unsigned)s * 128u + cl * 4];
            float e = q + edv; e = fmaxf(e, LEAKY * e);
            const float p = __expf(e);
            den += p;
            acc.x = fmaf(p, bf16val(u.x), acc.x);
            acc.y = fmaf(p, bf16val(u.y), acc.y);
            acc.z = fmaf(p, bf16val(u.z), acc.z);
            acc.w = fmaf(p, bf16val(u.w), acc.w);
        }
        const int jb = j + 2 + half;
        if (jb < deg) {
            const int s = cp[jb];
            const float q = es[(unsigned)s * 4u + head];
            const ushort4 u = *(const ushort4*)&Zb[(unsigned)s * 128u + cl * 4];
            float e = q + edv; e = fmaxf(e, LEAKY * e);
            const float p = __expf(e);
            den += p;
            acc.x = fmaf(p, bf16val(u.x), acc.x);
            acc.y = fmaf(p, bf16val(u.y), acc.y);
            acc.z = fmaf(p, bf16val(u.z), acc.z);
            acc.w = fmaf(p, bf16val(u.w), acc.w);
        }
    }

    den   += __shfl_xor(den, 32);
    acc.x += __shfl_xor(acc.x, 32);
    acc.y += __shfl_xor(acc.y, 32);
    acc.z += __shfl_xor(acc.z, 32);
    acc.w += __shfl_xor(acc.w, 32);

    if (half == 0) {
        float4 o;
        if (deg > 0) {
            const float r = 1.0f / den;
            o = make_float4(acc.x * r, acc.y * r, acc.z * r, acc.w * r);
        } else {
            o = make_float4(0.f, 0.f, 0.f, 0.f);
        }
        *(float4*)&Hout[(size_t)node * 128 + cl * 4] = o;
    }
}

__global__ __launch_bounds__(256) void gat_node1(
    const unsigned short* __restrict__ Zb, const float* __restrict__ es,
    const float* __restrict__ ed, const int* __restrict__ rowptr,
    const int* __restrict__ csrc, float* __restrict__ Hout, int N)
{
    const int lane = threadIdx.x & 63;
    const int node = (blockIdx.x * blockDim.x + threadIdx.x) >> 6;
    if (node >= N) return;

    const int grp = lane >> 3;
    const int cl  = lane & 7;
    const float edv = ed[node];
    const int beg = rowptr[node];
    const int deg = rowptr[node + 1] - beg;
    const int* __restrict__ cp = csrc + beg;

    float4 acc = make_float4(0.f, 0.f, 0.f, 0.f);
    float den = 0.f;

    int j = 0;
    for (; j + 8 <= deg; j += 8) {
        const int s = cp[j + grp];
        const float q = es[s];
        const ushort4 u = *(const ushort4*)&Zb[(unsigned)s * 32u + cl * 4];
        float e = q + edv; e = fmaxf(e, LEAKY * e);
        const float p = __expf(e);
        den += p;
        acc.x = fmaf(p, bf16val(u.x), acc.x);
        acc.y = fmaf(p, bf16val(u.y), acc.y);
        acc.z = fmaf(p, bf16val(u.z), acc.z);
        acc.w = fmaf(p, bf16val(u.w), acc.w);
    }
    {
        const int jt = j + grp;
        if (jt < deg) {
            const int s = cp[jt];
            const float q = es[s];
            const ushort4 u = *(const ushort4*)&Zb[(unsigned)s * 32u + cl * 4];
            float e = q + edv; e = fmaxf(e, LEAKY * e);
            const float p = __expf(e);
            den += p;
            acc.x = fmaf(p, bf16val(u.x), acc.x);
            acc.y = fmaf(p, bf16val(u.y), acc.y);
            acc.z = fmaf(p, bf16val(u.z), acc.z);
            acc.w = fmaf(p, bf16val(u.w), acc.w);
        }
    }

    #pragma unroll
    for (int off = 8; off < 64; off <<= 1) {
        den   += __shfl_xor(den, off);
        acc.x += __shfl_xor(acc.x, off);
        acc.y += __shfl_xor(acc.y, off);
        acc.z += __shfl_xor(acc.z, off);
        acc.w += __shfl_xor(acc.w, off);
    }

    if (grp == 0) {
        float4 o;
        if (deg > 0) {
            const float r = 1.0f / den;
            o = make_float4(acc.x * r, acc.y * r, acc.z * r, acc.w * r);
        } else {
            o = make_float4(0.f, 0.f, 0.f, 0.f);
        }
        *(float4*)&Hout[(size_t)node * 32 + cl * 4] = o;
    }
}

// =========================== launch ===========================
extern "C" void kernel_launch(void* const* d_in, const int* in_sizes, int n_in,
                              void* d_out, int out_size, void* d_ws, size_t ws_size,
                              hipStream_t stream) {
    const float* features = (const float*)d_in[0];
    const float* W1 = (const float*)d_in[1];
    const float* a1 = (const float*)d_in[2];
    const float* W2 = (const float*)d_in[3];
    const float* a2 = (const float*)d_in[4];
    const int*   src = (const int*)d_in[5];
    const int*   dst = (const int*)d_in[6];
    float* out = (float*)d_out;

    const int N  = in_sizes[0] / 128;   // 50000
    const int E  = in_sizes[5];         // 800000
    const int H1 = in_sizes[2] / 64;    // 4

    const int NB  = (N + 63) >> BSH;                      // 782 buckets (<= NBMAX)
    const int CAP = (((E / NB) * 3 / 2) + 255) & ~255;    // ~1.5x mean (1536)
    const int CPB = (E + SORTB - 1) / SORTB;              // edges per sort block (3125)

    // ---- workspace layout (16B-aligned blocks) ----
    char* wsb = (char*)d_ws;
    size_t ob = 0;
    auto alloc_b = [&](size_t bytes) {
        ob = (ob + 15) & ~(size_t)15;
        char* p = wsb + ob; ob += bytes; return p;
    };

    int* cnt    = (int*)alloc_b((size_t)N * 4);
    int* bcur   = (int*)alloc_b((size_t)NB * 4);
    int* hist   = (int*)alloc_b((size_t)SORTB * NB * 4);  // 256*782*4 = 800KB
    int* part   = (int*)alloc_b((size_t)N * 4);
    int* bsum   = (int*)alloc_b(256 * 4);
    int* rowptr = (int*)alloc_b((size_t)(N + 1) * 4);
    int* csrc   = (int*)alloc_b((size_t)E * 4);
    float* z1   = (float*)alloc_b((size_t)N * 128 * 4);
    float* h1   = (float*)alloc_b((size_t)N * 128 * 4);
    float* es1  = (float*)alloc_b((size_t)N * H1 * 4);
    float* ed1  = (float*)alloc_b((size_t)N * H1 * 4);
    float* z2   = (float*)alloc_b((size_t)N * 32 * 4);
    float* es2  = (float*)alloc_b((size_t)N * 4);
    float* ed2  = (float*)alloc_b((size_t)N * 4);
    unsigned short* zb1 = (unsigned short*)alloc_b((size_t)N * 128 * 2);
    unsigned short* zb2 = (unsigned short*)alloc_b((size_t)N * 32 * 2);

    // ebuf aliases z1: CSR build completes before gemm_t writes z1 (stream-ordered).
    // size: NB*CAP*8 = 782*1536*8 = 9.6MB <= N*128*4 = 25.6MB.
    uint2* ebuf = (uint2*)z1;

    const int B = 256;
    #define GRID(n) (((n) + B - 1) / B)
    const int nb = (N + SCAN_CHUNK - 1) / SCAN_CHUNK;

    // ---- CSR build (atomic-free stable bucket sort; reused by both layers) ----
    hist_blk<<<SORTB, 256, 0, stream>>>(dst, hist, E, NB, CPB);
    col_scan<<<GRID(NB * 64), 256, 0, stream>>>(hist, bcur, NB, SORTB);
    place_blk<<<SORTB, 256, 0, stream>>>(src, dst, hist, ebuf, E, NB, CPB, CAP);
    bucket_count<<<NB, 256, 0, stream>>>(ebuf, bcur, cnt, N, CAP);
    scan1<<<nb, B, 0, stream>>>(cnt, part, bsum, N);
    scan2<<<1, B, 0, stream>>>(bsum, nb);
    scan3<<<GRID(N + 1), B, 0, stream>>>(part, bsum, rowptr, N, E);
    bucket_place<<<NB, 256, 0, stream>>>(ebuf, bcur, rowptr, csrc, N, CAP);

    const int RB = (N + 63) / 64;   // 782 row blocks

    // ---- layer 1 (H=4, HD=128) ----
    gemm_t<64><<<dim3(RB, 2), 256, 0, stream>>>(features, W1, z1, zb1, N, 128);
    attn_coef<<<GRID(N * H1), B, 0, stream>>>(z1, a1, es1, ed1, N * H1, H1);
    gat_node4<<<GRID(N * 64), B, 0, stream>>>(zb1, es1, ed1, rowptr, csrc, h1, N);

    // ---- layer 2 (H=1, HD=32) ----
    gemm_t<32><<<dim3(RB, 1), 128, 0, stream>>>(h1, W2, z2, zb2, N, 32);
    attn_coef<<<GRID(N), B, 0, stream>>>(z2, a2, es2, ed2, N, 1);
    gat_node1<<<GRID(N * 64), B, 0, stream>>>(zb2, es2, ed2, rowptr, csrc, out, N);

    #undef GRID
    (void)n_in; (void)out_size; (void)ws_size;
}

// Round 16
// 227.980 us; speedup vs baseline: 1.8355x; 1.0913x over previous
//
#include <hip/hip_runtime.h>
#include <hip/hip_bf16.h>

#define LEAKY 0.2f
#define SCAN_CHUNK 1024
#define BSH 6                      // nodes per bucket = 64
#define NBMAX 1024                 // max buckets (LDS arrays)
#define SORTB 256                  // blocks in the stable counting sort

typedef __attribute__((ext_vector_type(2))) _Float16 half2v;
typedef __attribute__((ext_vector_type(8))) _Float16 half8v;

#if __has_builtin(__builtin_amdgcn_fdot2)
__device__ __forceinline__ float fdot2(half2v a, half2v b, float c) {
    return __builtin_amdgcn_fdot2(a, b, c, false);
}
#else
__device__ __forceinline__ float fdot2(half2v a, half2v b, float c) {
    return c + (float)a[0] * (float)b[0] + (float)a[1] * (float)b[1];
}
#endif

// ---------- bf16 bit helpers ----------
__device__ __forceinline__ unsigned short bf16bits(float f) {
    __hip_bfloat16 h = __float2bfloat16(f);
    return *reinterpret_cast<unsigned short*>(&h);
}
__device__ __forceinline__ float bf16val(unsigned short u) {
    unsigned v = (unsigned)u << 16;
    return __uint_as_float(v);
}

// ==================== CSR build: atomic-free stable bucket sort ====================
// (validated r15: hist/scan/place all sub-top-5, zero global atomics)

__global__ __launch_bounds__(256) void hist_blk(const int* __restrict__ dst,
                                                int* __restrict__ hist,
                                                int E, int NB, int CPB) {
    __shared__ int h[NBMAX];
    const int blk = blockIdx.x, t = threadIdx.x;
    for (int i = t; i < NB; i += 256) h[i] = 0;
    __syncthreads();
    const int e0 = blk * CPB, e1 = min(e0 + CPB, E);
    for (int e = e0 + t; e < e1; e += 256) atomicAdd(&h[dst[e] >> BSH], 1);
    __syncthreads();
    int* __restrict__ hr = hist + (size_t)blk * NB;
    for (int i = t; i < NB; i += 256) hr[i] = h[i];
}

__global__ __launch_bounds__(256) void col_scan(int* __restrict__ hist,
                                                int* __restrict__ bcur,
                                                int NB, int B) {
    const int lane = threadIdx.x & 63;
    const int b = (blockIdx.x * blockDim.x + threadIdx.x) >> 6;
    if (b >= NB) return;
    int run = 0;
    for (int base = 0; base < B; base += 64) {
        const int blk = base + lane;
        const int v = (blk < B) ? hist[(size_t)blk * NB + b] : 0;
        int s = v;
        #pragma unroll
        for (int off = 1; off < 64; off <<= 1) {
            int x = __shfl_up(s, off);
            if (lane >= off) s += x;
        }
        if (blk < B) hist[(size_t)blk * NB + b] = run + s - v;   // exclusive
        run += __shfl(s, 63);
    }
    if (lane == 0) bcur[b] = run;
}

__global__ __launch_bounds__(256) void place_blk(const int* __restrict__ src,
                                                 const int* __restrict__ dst,
                                                 const int* __restrict__ hist,
                                                 uint2* __restrict__ ebuf,
                                                 int E, int NB, int CPB, int CAP) {
    __shared__ int cur[NBMAX];
    const int blk = blockIdx.x, t = threadIdx.x;
    const int* __restrict__ hr = hist + (size_t)blk * NB;
    for (int i = t; i < NB; i += 256) cur[i] = hr[i];
    __syncthreads();
    const int e0 = blk * CPB, e1 = min(e0 + CPB, E);
    for (int e = e0 + t; e < e1; e += 256) {
        const int d = dst[e];
        const int b = d >> BSH;
        int pos = atomicAdd(&cur[b], 1);
        if (pos >= CAP) pos = CAP - 1;   // statistically unreachable
        ebuf[(size_t)b * CAP + pos] = make_uint2((unsigned)src[e], (unsigned)d);
    }
}

__global__ __launch_bounds__(256) void bucket_count(const uint2* __restrict__ ebuf,
                                                    const int* __restrict__ bcur,
                                                    int* __restrict__ cnt, int N, int CAP) {
    __shared__ int h[64];
    const int b  = blockIdx.x;
    const int n0 = b << BSH;
    const int t  = threadIdx.x;
    if (t < 64) h[t] = 0;
    __syncthreads();
    const int ne = min(bcur[b], CAP);
    const uint2* __restrict__ eb = ebuf + (size_t)b * CAP;
    for (int i = t; i < ne; i += 256) {
        atomicAdd(&h[(int)eb[i].y & 63], 1);
    }
    __syncthreads();
    if (t < 64 && n0 + t < N) cnt[n0 + t] = h[t];
}

__global__ __launch_bounds__(256) void bucket_place(const uint2* __restrict__ ebuf,
                                                    const int* __restrict__ bcur,
                                                    const int* __restrict__ rowptr,
                                                    int* __restrict__ csrc, int N, int CAP) {
    __shared__ int r[64];
    __shared__ int base[64];
    const int b  = blockIdx.x;
    const int n0 = b << BSH;
    const int t  = threadIdx.x;
    if (t < 64) {
        r[t] = 0;
        base[t] = (n0 + t < N) ? rowptr[n0 + t] : 0;
    }
    __syncthreads();
    const int ne = min(bcur[b], CAP);
    const uint2* __restrict__ eb = ebuf + (size_t)b * CAP;
    for (int i = t; i < ne; i += 256) {
        uint2 ed_ = eb[i];
        int li = (int)ed_.y & 63;
        int rk = atomicAdd(&r[li], 1);
        csrc[base[li] + rk] = (int)ed_.x;
    }
}

// ---------- scans (cnt -> rowptr) ----------
__global__ __launch_bounds__(256) void scan1(const int* __restrict__ cnt, int* __restrict__ part,
                                             int* __restrict__ bsum, int n) {
    __shared__ int s[256];
    const int base = blockIdx.x * SCAN_CHUNK;
    const int t = threadIdx.x;
    int v[4], sum = 0;
    #pragma unroll
    for (int i = 0; i < 4; ++i) {
        int idx = base + t * 4 + i;
        v[i] = (idx < n) ? cnt[idx] : 0;
        sum += v[i];
    }
    s[t] = sum;
    __syncthreads();
    for (int off = 1; off < 256; off <<= 1) {
        int x = (t >= off) ? s[t - off] : 0;
        __syncthreads();
        s[t] += x;
        __syncthreads();
    }
    int excl = (t == 0) ? 0 : s[t - 1];
    if (t == 255) bsum[blockIdx.x] = s[255];
    #pragma unroll
    for (int i = 0; i < 4; ++i) {
        int idx = base + t * 4 + i;
        if (idx < n) part[idx] = excl;
        excl += v[i];
    }
}

__global__ __launch_bounds__(256) void scan2(int* __restrict__ bsum, int nb) {
    __shared__ int s[256];
    const int t = threadIdx.x;
    s[t] = (t < nb) ? bsum[t] : 0;
    __syncthreads();
    for (int off = 1; off < 256; off <<= 1) {
        int x = (t >= off) ? s[t - off] : 0;
        __syncthreads();
        s[t] += x;
        __syncthreads();
    }
    if (t < nb) bsum[t] = (t == 0) ? 0 : s[t - 1];
}

__global__ void scan3(const int* __restrict__ part, const int* __restrict__ bsum,
                      int* __restrict__ rowptr, int n, int E) {
    int i = blockIdx.x * blockDim.x + threadIdx.x;
    if (i < n) rowptr[i] = part[i] + bsum[i / SCAN_CHUNK];
    if (i == n) rowptr[n] = E;
}

// ==================== z = X @ W — f16 dot2, FUSED attn_coef epilogue ====================
// Writes ONLY bf16 Zb (gat_node input) + es/ed. The fp32 z table is eliminated:
// es/ed are computed from acc directly via an 8-lane shfl reduce per (row, head).
template<int COLS>
__global__ __launch_bounds__(16 * COLS / 4) void gemm_t(
    const float* __restrict__ X, const float* __restrict__ W,
    const float* __restrict__ Aat, unsigned short* __restrict__ Zb,
    float* __restrict__ es, float* __restrict__ ed, int N, int HD, int H)
{
    constexpr int TC = COLS / 4;
    constexpr int NT = 16 * TC;
    __shared__ __align__(16) half2v XsT[64][68];
    __shared__ __align__(16) half2v Ws2[64][COLS];

    const int tid  = threadIdx.x;
    const int row0 = blockIdx.x * 64;
    const int col0 = blockIdx.y * COLS;

    for (int i = tid; i < 64 * 32; i += NT) {
        const int row = i >> 5, kq = i & 31;
        float4 xv = make_float4(0.f, 0.f, 0.f, 0.f);
        if (row0 + row < N) xv = *(const float4*)&X[(size_t)(row0 + row) * 128 + kq * 4];
        half2v a; a[0] = (_Float16)xv.x; a[1] = (_Float16)xv.y;
        half2v b; b[0] = (_Float16)xv.z; b[1] = (_Float16)xv.w;
        XsT[kq * 2][row]     = a;
        XsT[kq * 2 + 1][row] = b;
    }
    for (int i = tid; i < 64 * COLS; i += NT) {
        const int kp = i / COLS, c = i % COLS;
        const int hd = col0 + c;
        const size_t base = (size_t)(hd >> 5) * (128 * 32) + (hd & 31);
        half2v wv;
        wv[0] = (_Float16)W[base + (size_t)(2 * kp) * 32];
        wv[1] = (_Float16)W[base + (size_t)(2 * kp + 1) * 32];
        Ws2[kp][c] = wv;
    }
    __syncthreads();

    const int tr = tid / TC;
    const int tc = tid % TC;

    float acc[4][4] = {};
    #pragma unroll 4
    for (int kp = 0; kp < 64; ++kp) {
        half8v xv = *(const half8v*)&XsT[kp][tr * 4];
        half8v wv = *(const half8v*)&Ws2[kp][tc * 4];
        #pragma unroll
        for (int i = 0; i < 4; ++i) {
            half2v xi; xi[0] = xv[2 * i]; xi[1] = xv[2 * i + 1];
            #pragma unroll
            for (int j = 0; j < 4; ++j) {
                half2v wj; wj[0] = wv[2 * j]; wj[1] = wv[2 * j + 1];
                acc[i][j] = fdot2(xi, wj, acc[i][j]);
            }
        }
    }

    // ---- bf16 table write ----
    #pragma unroll
    for (int i = 0; i < 4; ++i) {
        const int row = row0 + tr * 4 + i;
        if (row < N) {
            ushort4 ub;
            ub.x = bf16bits(acc[i][0]); ub.y = bf16bits(acc[i][1]);
            ub.z = bf16bits(acc[i][2]); ub.w = bf16bits(acc[i][3]);
            *(ushort4*)&Zb[(size_t)row * HD + col0 + tc * 4] = ub;
        }
    }

    // ---- fused attn_coef: es/ed for this thread's head, reduced over the
    //      8 threads covering the head's 32 cols (8-aligned lane group) ----
    const int hg = (col0 + tc * 4) >> 5;          // global head
    const int cw = (tc & 7) * 4;                  // col-within-head base
    const float4 as4 = *(const float4*)&Aat[(size_t)hg * 64 + cw];
    const float4 ad4 = *(const float4*)&Aat[(size_t)hg * 64 + 32 + cw];
    #pragma unroll
    for (int i = 0; i < 4; ++i) {
        float se = acc[i][0] * as4.x + acc[i][1] * as4.y + acc[i][2] * as4.z + acc[i][3] * as4.w;
        float de = acc[i][0] * ad4.x + acc[i][1] * ad4.y + acc[i][2] * ad4.z + acc[i][3] * ad4.w;
        se += __shfl_xor(se, 1); de += __shfl_xor(de, 1);
        se += __shfl_xor(se, 2); de += __shfl_xor(de, 2);
        se += __shfl_xor(se, 4); de += __shfl_xor(de, 4);
        const int row = row0 + tr * 4 + i;
        if ((tc & 7) == 0 && row < N) {
            es[(size_t)row * H + hg] = se;
            ed[(size_t)row * H + hg] = de;
        }
    }
}

// ==================== fused per-node GAT, wide ushort4 gathers, deep ILP ====================
// Direct-exp softmax (validated): e ~ N(0,1), exp(e) <= ~400, fp32-safe.
#define EDGE4(sE)                                                              \
    {                                                                          \
        const int s_ = (sE);                                                   \
        const float q_ = es[(unsigned)s_ * 4u + head];                         \
        const ushort4 u_ = *(const ushort4*)&Zb[(unsigned)s_ * 128u + cl * 4]; \
        float e_ = q_ + edv; e_ = fmaxf(e_, LEAKY * e_);                       \
        const float p_ = __expf(e_);                                           \
        den += p_;                                                             \
        acc.x = fmaf(p_, bf16val(u_.x), acc.x);                                \
        acc.y = fmaf(p_, bf16val(u_.y), acc.y);                                \
        acc.z = fmaf(p_, bf16val(u_.z), acc.z);                                \
        acc.w = fmaf(p_, bf16val(u_.w), acc.w);                                \
    }

__global__ __launch_bounds__(256) void gat_node4(
    const unsigned short* __restrict__ Zb, const float* __restrict__ es,
    const float* __restrict__ ed, const int* __restrict__ rowptr,
    const int* __restrict__ csrc, float* __restrict__ Hout, int N)
{
    const int lane = threadIdx.x & 63;
    const int node = (blockIdx.x * blockDim.x + threadIdx.x) >> 6;
    if (node >= N) return;

    const int half = lane >> 5;
    const int cl   = lane & 31;
    const int head = cl >> 3;
    const float edv = ed[node * 4 + head];
    const int beg = rowptr[node];
    const int deg = rowptr[node + 1] - beg;
    const int* __restrict__ cp = csrc + beg;

    float4 acc = make_float4(0.f, 0.f, 0.f, 0.f);
    float den = 0.f;

    int j = 0;
    // 8 edges/iter (4 per half): 4 csrc + 4 es + 4 z-gathers in flight.
    for (; j + 8 <= deg; j += 8) {
        const int s0 = cp[j + half];
        const int s1 = cp[j + 2 + half];
        const int s2 = cp[j + 4 + half];
        const int s3 = cp[j + 6 + half];
        const float q0 = es[(unsigned)s0 * 4u + head];
        const float q1 = es[(unsigned)s1 * 4u + head];
        const float q2 = es[(unsigned)s2 * 4u + head];
        const float q3 = es[(unsigned)s3 * 4u + head];
        const ushort4 u0 = *(const ushort4*)&Zb[(unsigned)s0 * 128u + cl * 4];
        const ushort4 u1 = *(const ushort4*)&Zb[(unsigned)s1 * 128u + cl * 4];
        const ushort4 u2 = *(const ushort4*)&Zb[(unsigned)s2 * 128u + cl * 4];
        const ushort4 u3 = *(const ushort4*)&Zb[(unsigned)s3 * 128u + cl * 4];
        float e0 = q0 + edv; e0 = fmaxf(e0, LEAKY * e0);
        float e1 = q1 + edv; e1 = fmaxf(e1, LEAKY * e1);
        float e2 = q2 + edv; e2 = fmaxf(e2, LEAKY * e2);
        float e3 = q3 + edv; e3 = fmaxf(e3, LEAKY * e3);
        const float p0 = __expf(e0), p1 = __expf(e1);
        const float p2 = __expf(e2), p3 = __expf(e3);
        den += p0 + p1 + p2 + p3;
        acc.x = fmaf(p0, bf16val(u0.x), acc.x);
        acc.y = fmaf(p0, bf16val(u0.y), acc.y);
        acc.z = fmaf(p0, bf16val(u0.z), acc.z);
        acc.w = fmaf(p0, bf16val(u0.w), acc.w);
        acc.x = fmaf(p1, bf16val(u1.x), acc.x);
        acc.y = fmaf(p1, bf16val(u1.y), acc.y);
        acc.z = fmaf(p1, bf16val(u1.z), acc.z);
        acc.w = fmaf(p1, bf16val(u1.w), acc.w);
        acc.x = fmaf(p2, bf16val(u2.x), acc.x);
        acc.y = fmaf(p2, bf16val(u2.y), acc.y);
        acc.z = fmaf(p2, bf16val(u2.z), acc.z);
        acc.w = fmaf(p2, bf16val(u2.w), acc.w);
        acc.x = fmaf(p3, bf16val(u3.x), acc.x);
        acc.y = fmaf(p3, bf16val(u3.y), acc.y);
        acc.z = fmaf(p3, bf16val(u3.z), acc.z);
        acc.w = fmaf(p3, bf16val(u3.w), acc.w);
    }
    for (; j + 2 <= deg; j += 2) EDGE4(cp[j + half]);
    if (j < deg && half == 0)   EDGE4(cp[j]);      // odd leftover: half 0 only

    den   += __shfl_xor(den, 32);
    acc.x += __shfl_xor(acc.x, 32);
    acc.y += __shfl_xor(acc.y, 32);
    acc.z += __shfl_xor(acc.z, 32);
    acc.w += __shfl_xor(acc.w, 32);

    if (half == 0) {
        float4 o;
        if (deg > 0) {
            const float r = 1.0f / den;
            o = make_float4(acc.x * r, acc.y * r, acc.z * r, acc.w * r);
        } else {
            o = make_float4(0.f, 0.f, 0.f, 0.f);
        }
        *(float4*)&Hout[(size_t)node * 128 + cl * 4] = o;
    }
}

#define EDGE1(sE)                                                             \
    {                                                                         \
        const int s_ = (sE);                                                  \
        const float q_ = es[s_];                                              \
        const ushort4 u_ = *(const ushort4*)&Zb[(unsigned)s_ * 32u + cl * 4]; \
        float e_ = q_ + edv; e_ = fmaxf(e_, LEAKY * e_);                      \
        const float p_ = __expf(e_);                                          \
        den += p_;                                                            \
        acc.x = fmaf(p_, bf16val(u_.x), acc.x);                               \
        acc.y = fmaf(p_, bf16val(u_.y), acc.y);                               \
        acc.z = fmaf(p_, bf16val(u_.z), acc.z);                               \
        acc.w = fmaf(p_, bf16val(u_.w), acc.w);                               \
    }

__global__ __launch_bounds__(256) void gat_node1(
    const unsigned short* __restrict__ Zb, const float* __restrict__ es,
    const float* __restrict__ ed, const int* __restrict__ rowptr,
    const int* __restrict__ csrc, float* __restrict__ Hout, int N)
{
    const int lane = threadIdx.x & 63;
    const int node = (blockIdx.x * blockDim.x + threadIdx.x) >> 6;
    if (node >= N) return;

    const int grp = lane >> 3;
    const int cl  = lane & 7;
    const float edv = ed[node];
    const int beg = rowptr[node];
    const int deg = rowptr[node + 1] - beg;
    const int* __restrict__ cp = csrc + beg;

    float4 acc = make_float4(0.f, 0.f, 0.f, 0.f);
    float den = 0.f;

    int j = 0;
    for (; j + 16 <= deg; j += 16) {   // 2 edges per group in flight
        const int sA = cp[j + grp];
        const int sB = cp[j + 8 + grp];
        const float qA = es[sA], qB = es[sB];
        const ushort4 uA = *(const ushort4*)&Zb[(unsigned)sA * 32u + cl * 4];
        const ushort4 uB = *(const ushort4*)&Zb[(unsigned)sB * 32u + cl * 4];
        float eA = qA + edv; eA = fmaxf(eA, LEAKY * eA);
        float eB = qB + edv; eB = fmaxf(eB, LEAKY * eB);
        const float pA = __expf(eA), pB = __expf(eB);
        den += pA + pB;
        acc.x = fmaf(pA, bf16val(uA.x), acc.x);
        acc.y = fmaf(pA, bf16val(uA.y), acc.y);
        acc.z = fmaf(pA, bf16val(uA.z), acc.z);
        acc.w = fmaf(pA, bf16val(uA.w), acc.w);
        acc.x = fmaf(pB, bf16val(uB.x), acc.x);
        acc.y = fmaf(pB, bf16val(uB.y), acc.y);
        acc.z = fmaf(pB, bf16val(uB.z), acc.z);
        acc.w = fmaf(pB, bf16val(uB.w), acc.w);
    }
    for (; j + 8 <= deg; j += 8) EDGE1(cp[j + grp]);
    if (j + grp < deg)           EDGE1(cp[j + grp]);

    #pragma unroll
    for (int off = 8; off < 64; off <<= 1) {
        den   += __shfl_xor(den, off);
        acc.x += __shfl_xor(acc.x, off);
        acc.y += __shfl_xor(acc.y, off);
        acc.z += __shfl_xor(acc.z, off);
        acc.w += __shfl_xor(acc.w, off);
    }

    if (grp == 0) {
        float4 o;
        if (deg > 0) {
            const float r = 1.0f / den;
            o = make_float4(acc.x * r, acc.y * r, acc.z * r, acc.w * r);
        } else {
            o = make_float4(0.f, 0.f, 0.f, 0.f);
        }
        *(float4*)&Hout[(size_t)node * 32 + cl * 4] = o;
    }
}

// =========================== launch ===========================
extern "C" void kernel_launch(void* const* d_in, const int* in_sizes, int n_in,
                              void* d_out, int out_size, void* d_ws, size_t ws_size,
                              hipStream_t stream) {
    const float* features = (const float*)d_in[0];
    const float* W1 = (const float*)d_in[1];
    const float* a1 = (const float*)d_in[2];
    const float* W2 = (const float*)d_in[3];
    const float* a2 = (const float*)d_in[4];
    const int*   src = (const int*)d_in[5];
    const int*   dst = (const int*)d_in[6];
    float* out = (float*)d_out;

    const int N  = in_sizes[0] / 128;   // 50000
    const int E  = in_sizes[5];         // 800000
    const int H1 = in_sizes[2] / 64;    // 4

    const int NB  = (N + 63) >> BSH;                      // 782 buckets (<= NBMAX)
    const int CAP = (((E / NB) * 3 / 2) + 255) & ~255;    // ~1.5x mean (1536)
    const int CPB = (E + SORTB - 1) / SORTB;              // edges per sort block (3125)

    // ---- workspace layout (16B-aligned blocks) ----
    char* wsb = (char*)d_ws;
    size_t ob = 0;
    auto alloc_b = [&](size_t bytes) {
        ob = (ob + 15) & ~(size_t)15;
        char* p = wsb + ob; ob += bytes; return p;
    };

    int* cnt    = (int*)alloc_b((size_t)N * 4);
    int* bcur   = (int*)alloc_b((size_t)NB * 4);
    int* hist   = (int*)alloc_b((size_t)SORTB * NB * 4);  // 800KB
    int* part   = (int*)alloc_b((size_t)N * 4);
    int* bsum   = (int*)alloc_b(256 * 4);
    int* rowptr = (int*)alloc_b((size_t)(N + 1) * 4);
    int* csrc   = (int*)alloc_b((size_t)E * 4);
    uint2* ebuf = (uint2*)alloc_b((size_t)NB * CAP * 8);  // 9.6MB (standalone now)
    float* h1   = (float*)alloc_b((size_t)N * 128 * 4);
    float* es1  = (float*)alloc_b((size_t)N * H1 * 4);
    float* ed1  = (float*)alloc_b((size_t)N * H1 * 4);
    float* es2  = (float*)alloc_b((size_t)N * 4);
    float* ed2  = (float*)alloc_b((size_t)N * 4);
    unsigned short* zb1 = (unsigned short*)alloc_b((size_t)N * 128 * 2);
    unsigned short* zb2 = (unsigned short*)alloc_b((size_t)N * 32 * 2);

    const int B = 256;
    #define GRID(n) (((n) + B - 1) / B)
    const int nb = (N + SCAN_CHUNK - 1) / SCAN_CHUNK;

    // ---- CSR build (atomic-free stable bucket sort; reused by both layers) ----
    hist_blk<<<SORTB, 256, 0, stream>>>(dst, hist, E, NB, CPB);
    col_scan<<<GRID(NB * 64), 256, 0, stream>>>(hist, bcur, NB, SORTB);
    place_blk<<<SORTB, 256, 0, stream>>>(src, dst, hist, ebuf, E, NB, CPB, CAP);
    bucket_count<<<NB, 256, 0, stream>>>(ebuf, bcur, cnt, N, CAP);
    scan1<<<nb, B, 0, stream>>>(cnt, part, bsum, N);
    scan2<<<1, B, 0, stream>>>(bsum, nb);
    scan3<<<GRID(N + 1), B, 0, stream>>>(part, bsum, rowptr, N, E);
    bucket_place<<<NB, 256, 0, stream>>>(ebuf, bcur, rowptr, csrc, N, CAP);

    const int RB = (N + 63) / 64;   // 782 row blocks

    // ---- layer 1 (H=4, HD=128): gemm + fused attn_coef ----
    gemm_t<64><<<dim3(RB, 2), 256, 0, stream>>>(features, W1, a1, zb1, es1, ed1, N, 128, 4);
    gat_node4<<<GRID(N * 64), B, 0, stream>>>(zb1, es1, ed1, rowptr, csrc, h1, N);

    // ---- layer 2 (H=1, HD=32): gemm + fused attn_coef ----
    gemm_t<32><<<dim3(RB, 1), 128, 0, stream>>>(h1, W2, a2, zb2, es2, ed2, N, 32, 1);
    gat_node1<<<GRID(N * 64), B, 0, stream>>>(zb2, es2, ed2, rowptr, csrc, out, N);

    #undef GRID
    (void)n_in; (void)out_size; (void)ws_size;
}